// Round 4
// baseline (2406.896 us; speedup 1.0000x reference)
//
#include <hip/hip_runtime.h>
#include <hip/hip_bf16.h>

#define T_SEQ 4096
#define C_DIM 1024
#define H_HEADS 16
#define D_HEAD 64
#define QKVW 3072
#define WIN_HALF 128
#define GLOBAL_TOK 32

typedef __attribute__((ext_vector_type(8))) short bf16x8;
typedef __attribute__((ext_vector_type(4))) float f32x4;

__device__ __forceinline__ float bf2f(unsigned short u) {
    union { unsigned int i; float f; } c; c.i = ((unsigned int)u) << 16; return c.f;
}
__device__ __forceinline__ unsigned short f2bf(float f) {
    union { float f; unsigned int i; } c; c.f = f;
    return (unsigned short)((c.i + 0x7fffu + ((c.i >> 16) & 1u)) >> 16);
}

// f32 -> bf16 (RNE), vectorized x4. n4 = n/4.
__global__ __launch_bounds__(256) void cvt_f32_bf16_kernel(
    const float* __restrict__ src, unsigned short* __restrict__ dst, int n4)
{
    int idx = blockIdx.x * 256 + threadIdx.x;
    if (idx < n4) {
        float4 v = ((const float4*)src)[idx];
        ushort4 o;
        o.x = f2bf(v.x); o.y = f2bf(v.y); o.z = f2bf(v.z); o.w = f2bf(v.w);
        ((ushort4*)dst)[idx] = o;
    }
}

// C[m,n] = sum_k A[m,k]*B[k,n] + bias[n]; A,B bf16, bias f32, f32 accumulate.
// OUT_BF16 ? C bf16 : C f32.   Tile 64x64x32, 4 waves, MFMA 16x16x32 bf16.
// A-frag: A[m=lane&15][k=(lane>>4)*8+j]; B-frag: B[n=lane&15][k=...] (Bs transposed)
// C/D: col=lane&15, row=(lane>>4)*4+reg  [verified m89/m91; equivalence to naive
// GEMM proven by bit-identical round2/round3 outputs]
template<int OUT_BF16>
__global__ __launch_bounds__(256) void gemm_bias_kernel(
    const unsigned short* __restrict__ A,
    const unsigned short* __restrict__ B,
    const float* __restrict__ bias,
    void* __restrict__ Cv,
    int M, int N, int K)
{
    __shared__ unsigned short As[64][32];
    __shared__ unsigned short Bs[64][32];
    const int tid = threadIdx.x;
    const int m0 = blockIdx.y * 64;
    const int n0 = blockIdx.x * 64;
    const int w = tid >> 6;
    const int lane = tid & 63;
    const int quad = lane >> 4;
    const int r = lane & 15;

    const int arow = tid >> 2, akk = (tid & 3) << 3;   // 64 rows x 4x8 k
    const int bkrow = tid >> 3, bnn = (tid & 7) << 3;  // 32 k-rows x 8x8 n

    f32x4 acc[4];
    #pragma unroll
    for (int i = 0; i < 4; ++i) acc[i] = (f32x4){0.f, 0.f, 0.f, 0.f};

    for (int k0 = 0; k0 < K; k0 += 32) {
        uint4 av = *(const uint4*)(A + (size_t)(m0 + arow) * K + k0 + akk);
        uint4 bv = *(const uint4*)(B + (size_t)(k0 + bkrow) * N + n0 + bnn);
        *(uint4*)&As[arow][akk] = av;
        const unsigned short* bsp = (const unsigned short*)&bv;
        #pragma unroll
        for (int j = 0; j < 8; ++j) Bs[bnn + j][bkrow] = bsp[j];  // transpose
        __syncthreads();
        bf16x8 a = *(bf16x8*)&As[w * 16 + r][quad * 8];
        #pragma unroll
        for (int ct = 0; ct < 4; ++ct) {
            bf16x8 b = *(bf16x8*)&Bs[ct * 16 + r][quad * 8];
            acc[ct] = __builtin_amdgcn_mfma_f32_16x16x32_bf16(a, b, acc[ct], 0, 0, 0);
        }
        __syncthreads();
    }
    #pragma unroll
    for (int ct = 0; ct < 4; ++ct) {
        int col = n0 + ct * 16 + r;
        float bvv = bias[col];
        #pragma unroll
        for (int reg = 0; reg < 4; ++reg) {
            int row = m0 + w * 16 + quad * 4 + reg;
            if (OUT_BF16)
                ((unsigned short*)Cv)[(size_t)row * N + col] = f2bf(acc[ct][reg] + bvv);
            else
                ((float*)Cv)[(size_t)row * N + col] = acc[ct][reg] + bvv;
        }
    }
}

// One wave per (head h, q-row i). Online softmax over 64-col chunks.
// LDS-free: q and p broadcast across the wave via __shfl.
// Score phase: lane = column. PV phase: lane = d (coalesced v loads).
// All control flow is wave-uniform (depends only on per-wave i).
__global__ __launch_bounds__(256) void sparse_attn_kernel(
    const unsigned short* __restrict__ qkv,
    unsigned short* __restrict__ y)
{
    const int w = threadIdx.x >> 6;
    const int lane = threadIdx.x & 63;
    const int h = blockIdx.x >> 10;   // grid = H_HEADS * (T_SEQ/4)
    const int g = blockIdx.x & 1023;
    const int i = (g << 2) + w;       // q row for this wave

    const float qv = bf2f(qkv[(size_t)i * QKVW + h * 64 + lane]) * 0.125f;

    float m_run = -INFINITY;
    float l_run = 0.f;
    float acc = 0.f;  // out[d = lane]

    const unsigned short* kbase = qkv + (size_t)C_DIM + h * 64;
    const unsigned short* vbase = qkv + (size_t)(2 * C_DIM) + h * 64 + lane;

    // mask: i<32 -> all cols; else [0,32) U [max(32,i-128), min(T,i+129))
    int lo0, hi0, lo1, hi1;
    if (i < GLOBAL_TOK) { lo0 = 0; hi0 = T_SEQ; lo1 = 0; hi1 = 0; }
    else {
        lo0 = 0; hi0 = GLOBAL_TOK;
        lo1 = (i - WIN_HALF) > GLOBAL_TOK ? (i - WIN_HALF) : GLOBAL_TOK;
        hi1 = (i + WIN_HALF + 1) < T_SEQ ? (i + WIN_HALF + 1) : T_SEQ;
    }

    for (int range = 0; range < 2; ++range) {
        const int lo = range ? lo1 : lo0;
        const int hi = range ? hi1 : hi0;
        for (int c = lo; c < hi; c += 64) {
            const int col = c + lane;
            const bool valid = col < hi;
            const unsigned short* krow = kbase + (size_t)(valid ? col : c) * QKVW;
            float s = 0.f;
            #pragma unroll
            for (int d8 = 0; d8 < 8; ++d8) {
                uint4 kv = *(const uint4*)(krow + d8 * 8);
                const unsigned short* kk = (const unsigned short*)&kv;
                #pragma unroll
                for (int j = 0; j < 8; ++j)
                    s += __shfl(qv, d8 * 8 + j) * bf2f(kk[j]);
            }
            s = valid ? s : -INFINITY;
            float cm = s;
            #pragma unroll
            for (int off = 32; off; off >>= 1)
                cm = fmaxf(cm, __shfl_xor(cm, off));
            const float m_new = fmaxf(m_run, cm);
            const float alpha = expf(m_run - m_new);  // first chunk: exp(-inf)=0
            const float p = expf(s - m_new);          // invalid lanes: p = 0
            float psum = p;
            #pragma unroll
            for (int off = 32; off; off >>= 1)
                psum += __shfl_xor(psum, off);
            l_run = l_run * alpha + psum;
            m_run = m_new;
            acc *= alpha;
            const int len = (hi - c) < 64 ? (hi - c) : 64;
            const unsigned short* vp = vbase + (size_t)c * QKVW;
            for (int jj = 0; jj < len; ++jj)
                acc += __shfl(p, jj) * bf2f(vp[(size_t)jj * QKVW]);
        }
    }
    y[(size_t)i * C_DIM + h * 64 + lane] = f2bf(acc / l_run);
}

extern "C" void kernel_launch(void* const* d_in, const int* in_sizes, int n_in,
                              void* d_out, int out_size, void* d_ws, size_t ws_size,
                              hipStream_t stream) {
    const float* x  = (const float*)d_in[0];
    const float* Wa = (const float*)d_in[1];
    const float* ba = (const float*)d_in[2];
    const float* Wp = (const float*)d_in[3];
    const float* bp = (const float*)d_in[4];
    float* out = (float*)d_out;   // reference output dtype is float32

    // ws (ushort units): xb 4M, Wab 3M, Wpb 1M, qkv 12M, yat 4M = 48 MiB total
    unsigned short* xb  = (unsigned short*)d_ws;                    // [4096,1024]
    unsigned short* Wab = xb  + (size_t)T_SEQ * C_DIM;              // [1024,3072]
    unsigned short* Wpb = Wab + (size_t)C_DIM * QKVW;               // [1024,1024]
    unsigned short* qkv = Wpb + (size_t)C_DIM * C_DIM;              // [4096,3072]
    unsigned short* yat = qkv + (size_t)T_SEQ * QKVW;               // [4096,1024]

    const int n_x  = T_SEQ * C_DIM;
    const int n_Wa = C_DIM * QKVW;
    const int n_Wp = C_DIM * C_DIM;
    cvt_f32_bf16_kernel<<<n_x / 4 / 256, 256, 0, stream>>>(x, xb, n_x / 4);
    cvt_f32_bf16_kernel<<<n_Wa / 4 / 256, 256, 0, stream>>>(Wa, Wab, n_Wa / 4);
    cvt_f32_bf16_kernel<<<n_Wp / 4 / 256, 256, 0, stream>>>(Wp, Wpb, n_Wp / 4);

    gemm_bias_kernel<1><<<dim3(QKVW / 64, T_SEQ / 64), 256, 0, stream>>>(
        xb, Wab, ba, qkv, T_SEQ, QKVW, C_DIM);
    sparse_attn_kernel<<<H_HEADS * (T_SEQ / 4), 256, 0, stream>>>(qkv, yat);
    gemm_bias_kernel<0><<<dim3(C_DIM / 64, T_SEQ / 64), 256, 0, stream>>>(
        yat, Wpb, bp, out, T_SEQ, C_DIM, C_DIM);
}

// Round 5
// 688.797 us; speedup vs baseline: 3.4943x; 3.4943x over previous
//
#include <hip/hip_runtime.h>
#include <hip/hip_bf16.h>
#include <math.h>

#define T_SEQ 4096
#define C_DIM 1024
#define H_HEADS 16
#define D_HEAD 64
#define QKVW 3072
#define WIN_HALF 128
#define GLOBAL_TOK 32

typedef __attribute__((ext_vector_type(8))) short bf16x8;
typedef __attribute__((ext_vector_type(4))) float f32x4;

__device__ __forceinline__ float bf2f(unsigned short u) {
    union { unsigned int i; float f; } c; c.i = ((unsigned int)u) << 16; return c.f;
}
__device__ __forceinline__ unsigned short f2bf(float f) {
    union { float f; unsigned int i; } c; c.f = f;
    return (unsigned short)((c.i + 0x7fffu + ((c.i >> 16) & 1u)) >> 16);
}

// f32 -> bf16 (RNE), vectorized x4. n4 = n/4.
__global__ __launch_bounds__(256) void cvt_f32_bf16_kernel(
    const float* __restrict__ src, unsigned short* __restrict__ dst, int n4)
{
    int idx = blockIdx.x * 256 + threadIdx.x;
    if (idx < n4) {
        float4 v = ((const float4*)src)[idx];
        ushort4 o;
        o.x = f2bf(v.x); o.y = f2bf(v.y); o.z = f2bf(v.z); o.w = f2bf(v.w);
        ((ushort4*)dst)[idx] = o;
    }
}

// C[m,n] = sum_k A[m,k]*B[k,n] + bias[n]; A,B bf16, bias f32, f32 accumulate.
// OUT_BF16 ? C bf16 : C f32.   Tile 64x64x32, 4 waves, MFMA 16x16x32 bf16.
template<int OUT_BF16>
__global__ __launch_bounds__(256) void gemm_bias_kernel(
    const unsigned short* __restrict__ A,
    const unsigned short* __restrict__ B,
    const float* __restrict__ bias,
    void* __restrict__ Cv,
    int M, int N, int K)
{
    __shared__ unsigned short As[64][32];
    __shared__ unsigned short Bs[64][32];
    const int tid = threadIdx.x;
    const int m0 = blockIdx.y * 64;
    const int n0 = blockIdx.x * 64;
    const int w = tid >> 6;
    const int lane = tid & 63;
    const int quad = lane >> 4;
    const int r = lane & 15;

    const int arow = tid >> 2, akk = (tid & 3) << 3;
    const int bkrow = tid >> 3, bnn = (tid & 7) << 3;

    f32x4 acc[4];
    #pragma unroll
    for (int i = 0; i < 4; ++i) acc[i] = (f32x4){0.f, 0.f, 0.f, 0.f};

    for (int k0 = 0; k0 < K; k0 += 32) {
        uint4 av = *(const uint4*)(A + (size_t)(m0 + arow) * K + k0 + akk);
        uint4 bv = *(const uint4*)(B + (size_t)(k0 + bkrow) * N + n0 + bnn);
        *(uint4*)&As[arow][akk] = av;
        const unsigned short* bsp = (const unsigned short*)&bv;
        #pragma unroll
        for (int j = 0; j < 8; ++j) Bs[bnn + j][bkrow] = bsp[j];
        __syncthreads();
        bf16x8 a = *(bf16x8*)&As[w * 16 + r][quad * 8];
        #pragma unroll
        for (int ct = 0; ct < 4; ++ct) {
            bf16x8 b = *(bf16x8*)&Bs[ct * 16 + r][quad * 8];
            acc[ct] = __builtin_amdgcn_mfma_f32_16x16x32_bf16(a, b, acc[ct], 0, 0, 0);
        }
        __syncthreads();
    }
    #pragma unroll
    for (int ct = 0; ct < 4; ++ct) {
        int col = n0 + ct * 16 + r;
        float bvv = bias[col];
        #pragma unroll
        for (int reg = 0; reg < 4; ++reg) {
            int row = m0 + w * 16 + quad * 4 + reg;
            if (OUT_BF16)
                ((unsigned short*)Cv)[(size_t)row * N + col] = f2bf(acc[ct][reg] + bvv);
            else
                ((float*)Cv)[(size_t)row * N + col] = acc[ct][reg] + bvv;
        }
    }
}

// MFMA flash attention. Block = (head h, 64-row Q slab); wave w owns 16 rows.
// Per 32-col pair-tile: cooperative stage K (natural [c][d], = B-frag layout)
// and V^T (scalar-write transpose) in LDS; QK^T (4 mfma) -> mask -> online
// softmax (per (quad,reg) row) -> P via per-wave LDS round-trip (C-layout
// write, A-layout b128 read) -> PV (4 mfma into O C-frags).
// Tile order: global cols [0,32) FIRST (all rows valid there -> m_run finite
// before any fully-masked tile; such tiles then reduce to alpha=1,p=0).
#define KS_STRIDE 72
#define VT_STRIDE 40
#define PT_STRIDE 40
__global__ __launch_bounds__(256) void sparse_attn_mfma(
    const unsigned short* __restrict__ qkv,
    unsigned short* __restrict__ y)
{
    __shared__ unsigned short Ks[32 * KS_STRIDE];
    __shared__ unsigned short VT[64 * VT_STRIDE];
    __shared__ unsigned short Pt[4][16 * PT_STRIDE];

    const int tid = threadIdx.x;
    const int w = tid >> 6, lane = tid & 63;
    const int quad = lane >> 4, n = lane & 15;
    const int h = blockIdx.x >> 6;
    const int qblk = blockIdx.x & 63;
    const int q0 = qblk * 64;
    const int rowbase = q0 + w * 16;

    const int sc = tid >> 3, sdg = tid & 7;   // staging: col 0..31, d-group 0..7

    // Q A-frags (A[m=lane&15][k=quad*8+j]), loaded once
    const unsigned short* qptr = qkv + (size_t)(rowbase + n) * QKVW + h * 64 + quad * 8;
    bf16x8 a0 = *(const bf16x8*)qptr;
    bf16x8 a1 = *(const bf16x8*)(qptr + 32);

    f32x4 O[4];
    #pragma unroll
    for (int i = 0; i < 4; ++i) O[i] = (f32x4){0.f, 0.f, 0.f, 0.f};
    float m_run[4], l_run[4];
    #pragma unroll
    for (int r = 0; r < 4; ++r) { m_run[r] = -INFINITY; l_run[r] = 0.f; }

    int wlo, whi;
    if (qblk == 0) { wlo = GLOBAL_TOK; whi = T_SEQ; }
    else {
        int t = q0 - WIN_HALF; if (t < GLOBAL_TOK) t = GLOBAL_TOK;
        wlo = t & ~31;
        whi = q0 + 64 + WIN_HALF; if (whi > T_SEQ) whi = T_SEQ;  // q0+63+128+1
    }

    const unsigned short* kbase = qkv + C_DIM + h * 64;
    const unsigned short* vbase = qkv + 2 * C_DIM + h * 64;

    for (int c0 = 0; c0 < whi; c0 = (c0 == 0 ? wlo : c0 + 32)) {
        __syncthreads();
        // ---- cooperative staging: 32 cols x 64 d of K and V ----
        uint4 kvv = *(const uint4*)(kbase + (size_t)(c0 + sc) * QKVW + sdg * 8);
        uint4 vvv = *(const uint4*)(vbase + (size_t)(c0 + sc) * QKVW + sdg * 8);
        *(uint4*)&Ks[sc * KS_STRIDE + sdg * 8] = kvv;
        const unsigned short* vh = (const unsigned short*)&vvv;
        #pragma unroll
        for (int j = 0; j < 8; ++j) VT[(sdg * 8 + j) * VT_STRIDE + sc] = vh[j];
        __syncthreads();

        // ---- S = Q K^T for 32 cols (2 frags of 16) ----
        bf16x8 b00 = *(bf16x8*)&Ks[n * KS_STRIDE + quad * 8];
        bf16x8 b01 = *(bf16x8*)&Ks[n * KS_STRIDE + 32 + quad * 8];
        bf16x8 b10 = *(bf16x8*)&Ks[(n + 16) * KS_STRIDE + quad * 8];
        bf16x8 b11 = *(bf16x8*)&Ks[(n + 16) * KS_STRIDE + 32 + quad * 8];
        f32x4 Z = (f32x4){0.f, 0.f, 0.f, 0.f};
        f32x4 S0 = __builtin_amdgcn_mfma_f32_16x16x32_bf16(a0, b00, Z, 0, 0, 0);
        S0 = __builtin_amdgcn_mfma_f32_16x16x32_bf16(a1, b01, S0, 0, 0, 0);
        f32x4 S1 = __builtin_amdgcn_mfma_f32_16x16x32_bf16(a0, b10, Z, 0, 0, 0);
        S1 = __builtin_amdgcn_mfma_f32_16x16x32_bf16(a1, b11, S1, 0, 0, 0);

        // ---- mask + online softmax per row (row = rowbase + quad*4 + r) ----
        float alpha[4];
        #pragma unroll
        for (int r = 0; r < 4; ++r) {
            const int row = rowbase + quad * 4 + r;
            const int ca = c0 + n, cb = c0 + 16 + n;
            int da = row - ca; da = da < 0 ? -da : da;
            int db = row - cb; db = db < 0 ? -db : db;
            const bool va = (row < GLOBAL_TOK) || (ca < GLOBAL_TOK) || (da <= WIN_HALF);
            const bool vb = (row < GLOBAL_TOK) || (cb < GLOBAL_TOK) || (db <= WIN_HALF);
            float s0 = va ? S0[r] * 0.125f : -INFINITY;
            float s1 = vb ? S1[r] * 0.125f : -INFINITY;
            float mm = fmaxf(s0, s1);
            #pragma unroll
            for (int off = 1; off < 16; off <<= 1)
                mm = fmaxf(mm, __shfl_xor(mm, off));
            const float mn = fmaxf(m_run[r], mm);
            const float al = __expf(m_run[r] - mn);
            const float e0 = __expf(s0 - mn);
            const float e1 = __expf(s1 - mn);
            float rs = e0 + e1;
            #pragma unroll
            for (int off = 1; off < 16; off <<= 1)
                rs += __shfl_xor(rs, off);
            l_run[r] = l_run[r] * al + rs;
            m_run[r] = mn;
            alpha[r] = al;
            Pt[w][(quad * 4 + r) * PT_STRIDE + n] = f2bf(e0);
            Pt[w][(quad * 4 + r) * PT_STRIDE + 16 + n] = f2bf(e1);
        }
        #pragma unroll
        for (int dblk = 0; dblk < 4; ++dblk)
            #pragma unroll
            for (int r = 0; r < 4; ++r)
                O[dblk][r] *= alpha[r];

        // ---- PV: P[16x32] x V[32x64] ----
        bf16x8 pf = *(bf16x8*)&Pt[w][n * PT_STRIDE + quad * 8];
        #pragma unroll
        for (int dblk = 0; dblk < 4; ++dblk) {
            bf16x8 vf = *(bf16x8*)&VT[(dblk * 16 + n) * VT_STRIDE + quad * 8];
            O[dblk] = __builtin_amdgcn_mfma_f32_16x16x32_bf16(pf, vf, O[dblk], 0, 0, 0);
        }
    }

    // ---- epilogue: O / l -> y (bf16) ----
    #pragma unroll
    for (int dblk = 0; dblk < 4; ++dblk) {
        #pragma unroll
        for (int r = 0; r < 4; ++r) {
            const int row = rowbase + quad * 4 + r;
            y[(size_t)row * C_DIM + h * 64 + dblk * 16 + n] = f2bf(O[dblk][r] / l_run[r]);
        }
    }
}

extern "C" void kernel_launch(void* const* d_in, const int* in_sizes, int n_in,
                              void* d_out, int out_size, void* d_ws, size_t ws_size,
                              hipStream_t stream) {
    const float* x  = (const float*)d_in[0];
    const float* Wa = (const float*)d_in[1];
    const float* ba = (const float*)d_in[2];
    const float* Wp = (const float*)d_in[3];
    const float* bp = (const float*)d_in[4];
    float* out = (float*)d_out;

    // ws (ushort units): xb 4M, Wab 3M, Wpb 1M, qkv 12M, yat 4M = 48 MiB
    unsigned short* xb  = (unsigned short*)d_ws;
    unsigned short* Wab = xb  + (size_t)T_SEQ * C_DIM;
    unsigned short* Wpb = Wab + (size_t)C_DIM * QKVW;
    unsigned short* qkv = Wpb + (size_t)C_DIM * C_DIM;
    unsigned short* yat = qkv + (size_t)T_SEQ * QKVW;

    const int n_x  = T_SEQ * C_DIM;
    const int n_Wa = C_DIM * QKVW;
    const int n_Wp = C_DIM * C_DIM;
    cvt_f32_bf16_kernel<<<n_x / 4 / 256, 256, 0, stream>>>(x, xb, n_x / 4);
    cvt_f32_bf16_kernel<<<n_Wa / 4 / 256, 256, 0, stream>>>(Wa, Wab, n_Wa / 4);
    cvt_f32_bf16_kernel<<<n_Wp / 4 / 256, 256, 0, stream>>>(Wp, Wpb, n_Wp / 4);

    gemm_bias_kernel<1><<<dim3(QKVW / 64, T_SEQ / 64), 256, 0, stream>>>(
        xb, Wab, ba, qkv, T_SEQ, QKVW, C_DIM);
    sparse_attn_mfma<<<H_HEADS * (T_SEQ / 64), 256, 0, stream>>>(qkv, yat);
    gemm_bias_kernel<0><<<dim3(C_DIM / 64, T_SEQ / 64), 256, 0, stream>>>(
        yat, Wpb, bp, out, T_SEQ, C_DIM, C_DIM);
}

// Round 6
// 348.833 us; speedup vs baseline: 6.8998x; 1.9746x over previous
//
#include <hip/hip_runtime.h>
#include <hip/hip_bf16.h>
#include <math.h>

#define T_SEQ 4096
#define C_DIM 1024
#define H_HEADS 16
#define D_HEAD 64
#define QKVW 3072
#define WIN_HALF 128
#define GLOBAL_TOK 32

typedef __attribute__((ext_vector_type(8))) short bf16x8;
typedef __attribute__((ext_vector_type(4))) float f32x4;

__device__ __forceinline__ float bf2f(unsigned short u) {
    union { unsigned int i; float f; } c; c.i = ((unsigned int)u) << 16; return c.f;
}
__device__ __forceinline__ unsigned short f2bf(float f) {
    union { float f; unsigned int i; } c; c.f = f;
    return (unsigned short)((c.i + 0x7fffu + ((c.i >> 16) & 1u)) >> 16);
}

// f32 -> bf16 (RNE), vectorized x4. n4 = n/4.
__global__ __launch_bounds__(256) void cvt_f32_bf16_kernel(
    const float* __restrict__ src, unsigned short* __restrict__ dst, int n4)
{
    int idx = blockIdx.x * 256 + threadIdx.x;
    if (idx < n4) {
        float4 v = ((const float4*)src)[idx];
        ushort4 o;
        o.x = f2bf(v.x); o.y = f2bf(v.y); o.z = f2bf(v.z); o.w = f2bf(v.w);
        ((ushort4*)dst)[idx] = o;
    }
}

// C[m,n] = sum_k A[m,k]*B[k,n] + bias[n]; A,B bf16, bias f32, f32 accumulate.
// OUT_BF16 ? C bf16 : C f32.   Tile 64x64x32, 4 waves, MFMA 16x16x32 bf16.
template<int OUT_BF16>
__global__ __launch_bounds__(256) void gemm_bias_kernel(
    const unsigned short* __restrict__ A,
    const unsigned short* __restrict__ B,
    const float* __restrict__ bias,
    void* __restrict__ Cv,
    int M, int N, int K)
{
    __shared__ unsigned short As[64][32];
    __shared__ unsigned short Bs[64][32];
    const int tid = threadIdx.x;
    const int m0 = blockIdx.y * 64;
    const int n0 = blockIdx.x * 64;
    const int w = tid >> 6;
    const int lane = tid & 63;
    const int quad = lane >> 4;
    const int r = lane & 15;

    const int arow = tid >> 2, akk = (tid & 3) << 3;
    const int bkrow = tid >> 3, bnn = (tid & 7) << 3;

    f32x4 acc[4];
    #pragma unroll
    for (int i = 0; i < 4; ++i) acc[i] = (f32x4){0.f, 0.f, 0.f, 0.f};

    for (int k0 = 0; k0 < K; k0 += 32) {
        uint4 av = *(const uint4*)(A + (size_t)(m0 + arow) * K + k0 + akk);
        uint4 bv = *(const uint4*)(B + (size_t)(k0 + bkrow) * N + n0 + bnn);
        *(uint4*)&As[arow][akk] = av;
        const unsigned short* bsp = (const unsigned short*)&bv;
        #pragma unroll
        for (int j = 0; j < 8; ++j) Bs[bnn + j][bkrow] = bsp[j];
        __syncthreads();
        bf16x8 a = *(bf16x8*)&As[w * 16 + r][quad * 8];
        #pragma unroll
        for (int ct = 0; ct < 4; ++ct) {
            bf16x8 b = *(bf16x8*)&Bs[ct * 16 + r][quad * 8];
            acc[ct] = __builtin_amdgcn_mfma_f32_16x16x32_bf16(a, b, acc[ct], 0, 0, 0);
        }
        __syncthreads();
    }
    #pragma unroll
    for (int ct = 0; ct < 4; ++ct) {
        int col = n0 + ct * 16 + r;
        float bvv = bias[col];
        #pragma unroll
        for (int reg = 0; reg < 4; ++reg) {
            int row = m0 + w * 16 + quad * 4 + reg;
            if (OUT_BF16)
                ((unsigned short*)Cv)[(size_t)row * N + col] = f2bf(acc[ct][reg] + bvv);
            else
                ((float*)Cv)[(size_t)row * N + col] = acc[ct][reg] + bvv;
        }
    }
}

// MFMA flash attention, split-K for the dense (global) rows.
// Role A (bid < 1024): (head, 64-row slab). qblk>0: global tile + window
//   tiles, write y. qblk==0: cols [0,512) only; waves 0,1 (rows 0-31) emit
//   partial slot 0; waves 2,3 (rows 32-63, window subset of [0,192)) write y.
// Role B (bid >= 1024): (head, 256-col chunk of [512,4096)), rows 0-31 only
//   (all-valid: row<32 => global). Wave w: row-tile w>>1, tile-parity w&1,
//   4 tiles each, emits partial slot 1 + chunk*2 + parity.
// Partials: unnormalized O keyed to m_run, plus (m,l); merged by attn_combine.
#define KS_STRIDE 72
#define VT_STRIDE 40
#define PT_STRIDE 40
#define NSLOT 29
#define PROW 72
__global__ __launch_bounds__(256) void sparse_attn_mfma(
    const unsigned short* __restrict__ qkv,
    unsigned short* __restrict__ y,
    float* __restrict__ part)
{
    __shared__ unsigned short Ks[32 * KS_STRIDE];
    __shared__ unsigned short VT[64 * VT_STRIDE];
    __shared__ unsigned short Pt[4][16 * PT_STRIDE];

    const int tid = threadIdx.x;
    const int w = tid >> 6, lane = tid & 63;
    const int quad = lane >> 4, n = lane & 15;
    const int bid = blockIdx.x;
    const bool roleB = bid >= H_HEADS * (T_SEQ / 64);

    int h, rowbase, n_iter, qblk = 0, wlo = 0, colbase = 0, chunk = 0, rt = 0, sB = 0;
    if (!roleB) {
        h = bid >> 6; qblk = bid & 63;
        const int q0 = qblk * 64;
        rowbase = q0 + w * 16;
        int whi;
        if (qblk == 0) { wlo = GLOBAL_TOK; whi = 512; }
        else {
            int t = q0 - WIN_HALF; if (t < GLOBAL_TOK) t = GLOBAL_TOK;
            wlo = t & ~31;
            whi = q0 + 64 + WIN_HALF; if (whi > T_SEQ) whi = T_SEQ;
        }
        n_iter = 1 + (whi - wlo) / 32;
    } else {
        const int t = bid - H_HEADS * (T_SEQ / 64);
        h = t / 14; chunk = t % 14;
        colbase = 512 + chunk * 256;
        rt = w >> 1; sB = w & 1;
        rowbase = rt * 16;
        n_iter = 8;
    }

    const int sc = tid >> 3, sdg = tid & 7;   // staging: col 0..31, d-group 0..7

    // Q A-frags (A[m=lane&15][k=quad*8+j]), loaded once
    const unsigned short* qptr = qkv + (size_t)(rowbase + n) * QKVW + h * 64 + quad * 8;
    bf16x8 a0 = *(const bf16x8*)qptr;
    bf16x8 a1 = *(const bf16x8*)(qptr + 32);

    f32x4 O[4];
    #pragma unroll
    for (int i = 0; i < 4; ++i) O[i] = (f32x4){0.f, 0.f, 0.f, 0.f};
    float m_run[4], l_run[4];
    #pragma unroll
    for (int r = 0; r < 4; ++r) { m_run[r] = -INFINITY; l_run[r] = 0.f; }

    const unsigned short* kbase = qkv + C_DIM + h * 64;
    const unsigned short* vbase = qkv + 2 * C_DIM + h * 64;

    for (int it = 0; it < n_iter; ++it) {
        const int c0 = roleB ? (colbase + it * 32)
                             : (it == 0 ? 0 : wlo + (it - 1) * 32);
        __syncthreads();
        // ---- cooperative staging: 32 cols x 64 d of K and V ----
        uint4 kvv = *(const uint4*)(kbase + (size_t)(c0 + sc) * QKVW + sdg * 8);
        uint4 vvv = *(const uint4*)(vbase + (size_t)(c0 + sc) * QKVW + sdg * 8);
        *(uint4*)&Ks[sc * KS_STRIDE + sdg * 8] = kvv;
        const unsigned short* vh = (const unsigned short*)&vvv;
        #pragma unroll
        for (int j = 0; j < 8; ++j) VT[(sdg * 8 + j) * VT_STRIDE + sc] = vh[j];
        __syncthreads();

        if (roleB && ((it & 1) != sB)) continue;   // not my tile; barriers done

        // ---- S = Q K^T for 32 cols (2 frags of 16) ----
        bf16x8 b00 = *(bf16x8*)&Ks[n * KS_STRIDE + quad * 8];
        bf16x8 b01 = *(bf16x8*)&Ks[n * KS_STRIDE + 32 + quad * 8];
        bf16x8 b10 = *(bf16x8*)&Ks[(n + 16) * KS_STRIDE + quad * 8];
        bf16x8 b11 = *(bf16x8*)&Ks[(n + 16) * KS_STRIDE + 32 + quad * 8];
        f32x4 Z = (f32x4){0.f, 0.f, 0.f, 0.f};
        f32x4 S0 = __builtin_amdgcn_mfma_f32_16x16x32_bf16(a0, b00, Z, 0, 0, 0);
        S0 = __builtin_amdgcn_mfma_f32_16x16x32_bf16(a1, b01, S0, 0, 0, 0);
        f32x4 S1 = __builtin_amdgcn_mfma_f32_16x16x32_bf16(a0, b10, Z, 0, 0, 0);
        S1 = __builtin_amdgcn_mfma_f32_16x16x32_bf16(a1, b11, S1, 0, 0, 0);

        // ---- mask (role A only) + online softmax per row ----
        float alpha[4];
        #pragma unroll
        for (int r = 0; r < 4; ++r) {
            float s0 = S0[r] * 0.125f, s1 = S1[r] * 0.125f;
            if (!roleB) {
                const int row = rowbase + quad * 4 + r;
                const int ca = c0 + n, cb = c0 + 16 + n;
                int da = row - ca; da = da < 0 ? -da : da;
                int db = row - cb; db = db < 0 ? -db : db;
                const bool va = (row < GLOBAL_TOK) || (ca < GLOBAL_TOK) || (da <= WIN_HALF);
                const bool vb = (row < GLOBAL_TOK) || (cb < GLOBAL_TOK) || (db <= WIN_HALF);
                if (!va) s0 = -INFINITY;
                if (!vb) s1 = -INFINITY;
            }
            float mm = fmaxf(s0, s1);
            #pragma unroll
            for (int off = 1; off < 16; off <<= 1)
                mm = fmaxf(mm, __shfl_xor(mm, off));
            const float mn = fmaxf(m_run[r], mm);
            const float al = __expf(m_run[r] - mn);
            const float e0 = __expf(s0 - mn);
            const float e1 = __expf(s1 - mn);
            float rs = e0 + e1;
            #pragma unroll
            for (int off = 1; off < 16; off <<= 1)
                rs += __shfl_xor(rs, off);
            l_run[r] = l_run[r] * al + rs;
            m_run[r] = mn;
            alpha[r] = al;
            Pt[w][(quad * 4 + r) * PT_STRIDE + n] = f2bf(e0);
            Pt[w][(quad * 4 + r) * PT_STRIDE + 16 + n] = f2bf(e1);
        }
        #pragma unroll
        for (int dblk = 0; dblk < 4; ++dblk)
            #pragma unroll
            for (int r = 0; r < 4; ++r)
                O[dblk][r] *= alpha[r];

        // ---- PV: P[16x32] x V[32x64] ----
        bf16x8 pf = *(bf16x8*)&Pt[w][n * PT_STRIDE + quad * 8];
        #pragma unroll
        for (int dblk = 0; dblk < 4; ++dblk) {
            bf16x8 vf = *(bf16x8*)&VT[(dblk * 16 + n) * VT_STRIDE + quad * 8];
            O[dblk] = __builtin_amdgcn_mfma_f32_16x16x32_bf16(pf, vf, O[dblk], 0, 0, 0);
        }
    }

    // ---- epilogue ----
    const bool partial = roleB || (qblk == 0 && w < 2);
    if (!partial) {
        #pragma unroll
        for (int dblk = 0; dblk < 4; ++dblk)
            #pragma unroll
            for (int r = 0; r < 4; ++r) {
                const int row = rowbase + quad * 4 + r;
                y[(size_t)row * C_DIM + h * 64 + dblk * 16 + n] =
                    f2bf(O[dblk][r] / l_run[r]);
            }
    } else {
        const int rtE = roleB ? rt : w;           // role A: w in {0,1} == row-tile
        const int slot = roleB ? (1 + chunk * 2 + sB) : 0;
        float* pb = part + ((size_t)(h * 2 + rtE) * NSLOT + slot) * 16 * PROW;
        #pragma unroll
        for (int dblk = 0; dblk < 4; ++dblk)
            #pragma unroll
            for (int r = 0; r < 4; ++r)
                pb[(quad * 4 + r) * PROW + dblk * 16 + n] = O[dblk][r];
        if (n == 0) {
            #pragma unroll
            for (int r = 0; r < 4; ++r) {
                pb[(quad * 4 + r) * PROW + 64] = m_run[r];
                pb[(quad * 4 + r) * PROW + 65] = l_run[r];
            }
        }
    }
}

// Merge NSLOT partials per (head, 16-row tile) -> y rows 0..31.
__global__ __launch_bounds__(64) void attn_combine(
    const float* __restrict__ part, unsigned short* __restrict__ y)
{
    const int d = threadIdx.x;
    const int h = blockIdx.x >> 1, rt = blockIdx.x & 1;
    const float* base = part + (size_t)(h * 2 + rt) * NSLOT * 16 * PROW;
    for (int row = 0; row < 16; ++row) {
        float M = -INFINITY;
        for (int sl = 0; sl < NSLOT; ++sl)
            M = fmaxf(M, base[(size_t)sl * 16 * PROW + row * PROW + 64]);
        float L = 0.f, Od = 0.f;
        for (int sl = 0; sl < NSLOT; ++sl) {
            const float* p = base + (size_t)sl * 16 * PROW + row * PROW;
            const float s = __expf(p[64] - M);
            L += p[65] * s;
            Od += p[d] * s;
        }
        y[(size_t)(rt * 16 + row) * C_DIM + h * 64 + d] = f2bf(Od / L);
    }
}

extern "C" void kernel_launch(void* const* d_in, const int* in_sizes, int n_in,
                              void* d_out, int out_size, void* d_ws, size_t ws_size,
                              hipStream_t stream) {
    const float* x  = (const float*)d_in[0];
    const float* Wa = (const float*)d_in[1];
    const float* ba = (const float*)d_in[2];
    const float* Wp = (const float*)d_in[3];
    const float* bp = (const float*)d_in[4];
    float* out = (float*)d_out;

    // ws (ushort units): xb 4M, Wab 3M, Wpb 1M, qkv 12M, yat 4M = 48 MiB
    unsigned short* xb  = (unsigned short*)d_ws;
    unsigned short* Wab = xb  + (size_t)T_SEQ * C_DIM;
    unsigned short* Wpb = Wab + (size_t)C_DIM * QKVW;
    unsigned short* qkv = Wpb + (size_t)C_DIM * C_DIM;
    unsigned short* yat = qkv + (size_t)T_SEQ * QKVW;
    // attention partials reuse the xb region (dead after GEMM1; stream-ordered)
    float* part = (float*)d_ws;   // 16*2*29*16*72 f32 = 4.28 MB < 8 MiB

    const int n_x  = T_SEQ * C_DIM;
    const int n_Wa = C_DIM * QKVW;
    const int n_Wp = C_DIM * C_DIM;
    cvt_f32_bf16_kernel<<<n_x / 4 / 256, 256, 0, stream>>>(x, xb, n_x / 4);
    cvt_f32_bf16_kernel<<<n_Wa / 4 / 256, 256, 0, stream>>>(Wa, Wab, n_Wa / 4);
    cvt_f32_bf16_kernel<<<n_Wp / 4 / 256, 256, 0, stream>>>(Wp, Wpb, n_Wp / 4);

    gemm_bias_kernel<1><<<dim3(QKVW / 64, T_SEQ / 64), 256, 0, stream>>>(
        xb, Wab, ba, qkv, T_SEQ, QKVW, C_DIM);

    const int nA = H_HEADS * (T_SEQ / 64);          // 1024
    const int nB = H_HEADS * 14;                    // 224
    sparse_attn_mfma<<<nA + nB, 256, 0, stream>>>(qkv, yat, part);
    attn_combine<<<H_HEADS * 2, 64, 0, stream>>>(part, yat);

    gemm_bias_kernel<0><<<dim3(C_DIM / 64, T_SEQ / 64), 256, 0, stream>>>(
        yat, Wpb, bp, out, T_SEQ, C_DIM, C_DIM);
}

// Round 7
// 238.250 us; speedup vs baseline: 10.1024x; 1.4641x over previous
//
#include <hip/hip_runtime.h>
#include <hip/hip_bf16.h>
#include <math.h>

#define T_SEQ 4096
#define C_DIM 1024
#define H_HEADS 16
#define D_HEAD 64
#define QKVW 3072
#define WIN_HALF 128
#define GLOBAL_TOK 32

typedef __attribute__((ext_vector_type(8))) short bf16x8;
typedef __attribute__((ext_vector_type(4))) float f32x4;

__device__ __forceinline__ float bf2f(unsigned short u) {
    union { unsigned int i; float f; } c; c.i = ((unsigned int)u) << 16; return c.f;
}
__device__ __forceinline__ unsigned short f2bf(float f) {
    union { float f; unsigned int i; } c; c.f = f;
    return (unsigned short)((c.i + 0x7fffu + ((c.i >> 16) & 1u)) >> 16);
}

// async global->LDS, 16B per lane; LDS dest = wave-uniform base + lane*16
// [m03/m97: HW-verified on gfx950]
__device__ __forceinline__ void gll16(const unsigned short* g, unsigned short* l) {
    __builtin_amdgcn_global_load_lds(
        (const __attribute__((address_space(1))) void*)g,
        (__attribute__((address_space(3))) void*)l, 16, 0, 0);
}

// f32 -> bf16 (RNE), vectorized x4. n4 = n/4.
__global__ __launch_bounds__(256) void cvt_f32_bf16_kernel(
    const float* __restrict__ src, unsigned short* __restrict__ dst, int n4)
{
    int idx = blockIdx.x * 256 + threadIdx.x;
    if (idx < n4) {
        float4 v = ((const float4*)src)[idx];
        ushort4 o;
        o.x = f2bf(v.x); o.y = f2bf(v.y); o.z = f2bf(v.z); o.w = f2bf(v.w);
        ((ushort4*)dst)[idx] = o;
    }
}

// W [R][Ncols] f32  ->  Wt [Ncols][R] bf16  (32x32 tiles via LDS)
__global__ __launch_bounds__(256) void cvt_transpose_kernel(
    const float* __restrict__ src, unsigned short* __restrict__ dst,
    int R, int Ncols)
{
    __shared__ unsigned short tile[32][36];
    const int r0 = blockIdx.y * 32, c0 = blockIdx.x * 32;
    const int t = threadIdx.x;
    const int rr = t >> 3, cq = (t & 7) * 4;
    float4 v = *(const float4*)(src + (size_t)(r0 + rr) * Ncols + c0 + cq);
    tile[rr][cq + 0] = f2bf(v.x); tile[rr][cq + 1] = f2bf(v.y);
    tile[rr][cq + 2] = f2bf(v.z); tile[rr][cq + 3] = f2bf(v.w);
    __syncthreads();
    const int cc = t >> 3, rq = (t & 7) * 4;
    ushort4 o;
    o.x = tile[rq + 0][cc]; o.y = tile[rq + 1][cc];
    o.z = tile[rq + 2][cc]; o.w = tile[rq + 3][cc];
    *(ushort4*)(dst + (size_t)(c0 + cc) * R + r0 + rq) = o;
}

// C[m,n] = sum_k A[m,k]*Bt[n,k] + bias[n]; A,Bt bf16, f32 accumulate.
// m97 recipe: 128x128x32 tile, 4 waves (2x2 of 64x64), 4x4 acc/wave,
// global_load_lds width=16 staging (no ds_write, no VGPR round-trip),
// natural [128][32] LDS layout (contiguous in lane order — required).
// A-frag: A[m=lane&15][k=quad*8+j]; C/D: col=lane&15, row=quad*4+reg.
template<int OUT_BF16>
__global__ __launch_bounds__(256) void gemm_nt_kernel(
    const unsigned short* __restrict__ A,    // [M,K]
    const unsigned short* __restrict__ Bt,   // [N,K]
    const float* __restrict__ bias,          // [N]
    void* __restrict__ Cv, int M, int N, int K)
{
    __shared__ unsigned short As[128 * 32];
    __shared__ unsigned short Bs[128 * 32];
    const int tid = threadIdx.x;
    const int w = tid >> 6, lane = tid & 63;
    const int quad = lane >> 4, r16 = lane & 15;
    const int m0 = blockIdx.y * 128, n0 = blockIdx.x * 128;
    const int wm = (w & 1) * 64, wn = (w >> 1) * 64;

    f32x4 acc[4][4];
    #pragma unroll
    for (int i = 0; i < 4; ++i)
        #pragma unroll
        for (int j = 0; j < 4; ++j) acc[i][j] = (f32x4){0.f, 0.f, 0.f, 0.f};

    const unsigned short* Ab = A + (size_t)m0 * K;
    const unsigned short* Bb = Bt + (size_t)n0 * K;

    for (int k0 = 0; k0 < K; k0 += 32) {
        __syncthreads();
        // stage A,B tiles: chunk = w*128 + i*64 + lane; row=chunk>>2, kcol=(chunk&3)*8
        #pragma unroll
        for (int i = 0; i < 2; ++i) {
            const int chunk = w * 128 + i * 64 + lane;
            const int row = chunk >> 2, kc = (chunk & 3) * 8;
            gll16(Ab + (size_t)row * K + k0 + kc, &As[(w * 2 + i) * 512]);
            gll16(Bb + (size_t)row * K + k0 + kc, &Bs[(w * 2 + i) * 512]);
        }
        asm volatile("s_waitcnt vmcnt(0)" ::: "memory");
        __syncthreads();

        bf16x8 af[4], bf_[4];
        #pragma unroll
        for (int t = 0; t < 4; ++t) {
            af[t]  = *(const bf16x8*)&As[(wm + t * 16 + r16) * 32 + quad * 8];
            bf_[t] = *(const bf16x8*)&Bs[(wn + t * 16 + r16) * 32 + quad * 8];
        }
        #pragma unroll
        for (int mt = 0; mt < 4; ++mt)
            #pragma unroll
            for (int nt = 0; nt < 4; ++nt)
                acc[mt][nt] = __builtin_amdgcn_mfma_f32_16x16x32_bf16(
                    af[mt], bf_[nt], acc[mt][nt], 0, 0, 0);
    }

    #pragma unroll
    for (int nt = 0; nt < 4; ++nt) {
        const int col = n0 + wn + nt * 16 + r16;
        const float bv = bias[col];
        #pragma unroll
        for (int mt = 0; mt < 4; ++mt)
            #pragma unroll
            for (int reg = 0; reg < 4; ++reg) {
                const int row = m0 + wm + mt * 16 + quad * 4 + reg;
                if (OUT_BF16)
                    ((unsigned short*)Cv)[(size_t)row * N + col] = f2bf(acc[mt][nt][reg] + bv);
                else
                    ((float*)Cv)[(size_t)row * N + col] = acc[mt][nt][reg] + bv;
            }
    }
}

// MFMA flash attention, split-K for the dense (global) rows. (unchanged r6)
#define KS_STRIDE 72
#define VT_STRIDE 40
#define PT_STRIDE 40
#define NSLOT 29
#define PROW 72
__global__ __launch_bounds__(256) void sparse_attn_mfma(
    const unsigned short* __restrict__ qkv,
    unsigned short* __restrict__ y,
    float* __restrict__ part)
{
    __shared__ unsigned short Ks[32 * KS_STRIDE];
    __shared__ unsigned short VT[64 * VT_STRIDE];
    __shared__ unsigned short Pt[4][16 * PT_STRIDE];

    const int tid = threadIdx.x;
    const int w = tid >> 6, lane = tid & 63;
    const int quad = lane >> 4, n = lane & 15;
    const int bid = blockIdx.x;
    const bool roleB = bid >= H_HEADS * (T_SEQ / 64);

    int h, rowbase, n_iter, qblk = 0, wlo = 0, colbase = 0, chunk = 0, rt = 0, sB = 0;
    if (!roleB) {
        h = bid >> 6; qblk = bid & 63;
        const int q0 = qblk * 64;
        rowbase = q0 + w * 16;
        int whi;
        if (qblk == 0) { wlo = GLOBAL_TOK; whi = 512; }
        else {
            int t = q0 - WIN_HALF; if (t < GLOBAL_TOK) t = GLOBAL_TOK;
            wlo = t & ~31;
            whi = q0 + 64 + WIN_HALF; if (whi > T_SEQ) whi = T_SEQ;
        }
        n_iter = 1 + (whi - wlo) / 32;
    } else {
        const int t = bid - H_HEADS * (T_SEQ / 64);
        h = t / 14; chunk = t % 14;
        colbase = 512 + chunk * 256;
        rt = w >> 1; sB = w & 1;
        rowbase = rt * 16;
        n_iter = 8;
    }

    const int sc = tid >> 3, sdg = tid & 7;

    const unsigned short* qptr = qkv + (size_t)(rowbase + n) * QKVW + h * 64 + quad * 8;
    bf16x8 a0 = *(const bf16x8*)qptr;
    bf16x8 a1 = *(const bf16x8*)(qptr + 32);

    f32x4 O[4];
    #pragma unroll
    for (int i = 0; i < 4; ++i) O[i] = (f32x4){0.f, 0.f, 0.f, 0.f};
    float m_run[4], l_run[4];
    #pragma unroll
    for (int r = 0; r < 4; ++r) { m_run[r] = -INFINITY; l_run[r] = 0.f; }

    const unsigned short* kbase = qkv + C_DIM + h * 64;
    const unsigned short* vbase = qkv + 2 * C_DIM + h * 64;

    for (int it = 0; it < n_iter; ++it) {
        const int c0 = roleB ? (colbase + it * 32)
                             : (it == 0 ? 0 : wlo + (it - 1) * 32);
        __syncthreads();
        uint4 kvv = *(const uint4*)(kbase + (size_t)(c0 + sc) * QKVW + sdg * 8);
        uint4 vvv = *(const uint4*)(vbase + (size_t)(c0 + sc) * QKVW + sdg * 8);
        *(uint4*)&Ks[sc * KS_STRIDE + sdg * 8] = kvv;
        const unsigned short* vh = (const unsigned short*)&vvv;
        #pragma unroll
        for (int j = 0; j < 8; ++j) VT[(sdg * 8 + j) * VT_STRIDE + sc] = vh[j];
        __syncthreads();

        if (roleB && ((it & 1) != sB)) continue;

        bf16x8 b00 = *(bf16x8*)&Ks[n * KS_STRIDE + quad * 8];
        bf16x8 b01 = *(bf16x8*)&Ks[n * KS_STRIDE + 32 + quad * 8];
        bf16x8 b10 = *(bf16x8*)&Ks[(n + 16) * KS_STRIDE + quad * 8];
        bf16x8 b11 = *(bf16x8*)&Ks[(n + 16) * KS_STRIDE + 32 + quad * 8];
        f32x4 Z = (f32x4){0.f, 0.f, 0.f, 0.f};
        f32x4 S0 = __builtin_amdgcn_mfma_f32_16x16x32_bf16(a0, b00, Z, 0, 0, 0);
        S0 = __builtin_amdgcn_mfma_f32_16x16x32_bf16(a1, b01, S0, 0, 0, 0);
        f32x4 S1 = __builtin_amdgcn_mfma_f32_16x16x32_bf16(a0, b10, Z, 0, 0, 0);
        S1 = __builtin_amdgcn_mfma_f32_16x16x32_bf16(a1, b11, S1, 0, 0, 0);

        float alpha[4];
        #pragma unroll
        for (int r = 0; r < 4; ++r) {
            float s0 = S0[r] * 0.125f, s1 = S1[r] * 0.125f;
            if (!roleB) {
                const int row = rowbase + quad * 4 + r;
                const int ca = c0 + n, cb = c0 + 16 + n;
                int da = row - ca; da = da < 0 ? -da : da;
                int db = row - cb; db = db < 0 ? -db : db;
                const bool va = (row < GLOBAL_TOK) || (ca < GLOBAL_TOK) || (da <= WIN_HALF);
                const bool vb = (row < GLOBAL_TOK) || (cb < GLOBAL_TOK) || (db <= WIN_HALF);
                if (!va) s0 = -INFINITY;
                if (!vb) s1 = -INFINITY;
            }
            float mm = fmaxf(s0, s1);
            #pragma unroll
            for (int off = 1; off < 16; off <<= 1)
                mm = fmaxf(mm, __shfl_xor(mm, off));
            const float mn = fmaxf(m_run[r], mm);
            const float al = __expf(m_run[r] - mn);
            const float e0 = __expf(s0 - mn);
            const float e1 = __expf(s1 - mn);
            float rs = e0 + e1;
            #pragma unroll
            for (int off = 1; off < 16; off <<= 1)
                rs += __shfl_xor(rs, off);
            l_run[r] = l_run[r] * al + rs;
            m_run[r] = mn;
            alpha[r] = al;
            Pt[w][(quad * 4 + r) * PT_STRIDE + n] = f2bf(e0);
            Pt[w][(quad * 4 + r) * PT_STRIDE + 16 + n] = f2bf(e1);
        }
        #pragma unroll
        for (int dblk = 0; dblk < 4; ++dblk)
            #pragma unroll
            for (int r = 0; r < 4; ++r)
                O[dblk][r] *= alpha[r];

        bf16x8 pf = *(bf16x8*)&Pt[w][n * PT_STRIDE + quad * 8];
        #pragma unroll
        for (int dblk = 0; dblk < 4; ++dblk) {
            bf16x8 vf = *(bf16x8*)&VT[(dblk * 16 + n) * VT_STRIDE + quad * 8];
            O[dblk] = __builtin_amdgcn_mfma_f32_16x16x32_bf16(pf, vf, O[dblk], 0, 0, 0);
        }
    }

    const bool partial = roleB || (qblk == 0 && w < 2);
    if (!partial) {
        #pragma unroll
        for (int dblk = 0; dblk < 4; ++dblk)
            #pragma unroll
            for (int r = 0; r < 4; ++r) {
                const int row = rowbase + quad * 4 + r;
                y[(size_t)row * C_DIM + h * 64 + dblk * 16 + n] =
                    f2bf(O[dblk][r] / l_run[r]);
            }
    } else {
        const int rtE = roleB ? rt : w;
        const int slot = roleB ? (1 + chunk * 2 + sB) : 0;
        float* pb = part + ((size_t)(h * 2 + rtE) * NSLOT + slot) * 16 * PROW;
        #pragma unroll
        for (int dblk = 0; dblk < 4; ++dblk)
            #pragma unroll
            for (int r = 0; r < 4; ++r)
                pb[(quad * 4 + r) * PROW + dblk * 16 + n] = O[dblk][r];
        if (n == 0) {
            #pragma unroll
            for (int r = 0; r < 4; ++r) {
                pb[(quad * 4 + r) * PROW + 64] = m_run[r];
                pb[(quad * 4 + r) * PROW + 65] = l_run[r];
            }
        }
    }
}

// Merge NSLOT partials per (head, 16-row tile) -> y rows 0..31.
__global__ __launch_bounds__(64) void attn_combine(
    const float* __restrict__ part, unsigned short* __restrict__ y)
{
    const int d = threadIdx.x;
    const int h = blockIdx.x >> 1, rt = blockIdx.x & 1;
    const float* base = part + (size_t)(h * 2 + rt) * NSLOT * 16 * PROW;
    for (int row = 0; row < 16; ++row) {
        float M = -INFINITY;
        for (int sl = 0; sl < NSLOT; ++sl)
            M = fmaxf(M, base[(size_t)sl * 16 * PROW + row * PROW + 64]);
        float L = 0.f, Od = 0.f;
        for (int sl = 0; sl < NSLOT; ++sl) {
            const float* p = base + (size_t)sl * 16 * PROW + row * PROW;
            const float s = __expf(p[64] - M);
            L += p[65] * s;
            Od += p[d] * s;
        }
        y[(size_t)(rt * 16 + row) * C_DIM + h * 64 + d] = f2bf(Od / L);
    }
}

extern "C" void kernel_launch(void* const* d_in, const int* in_sizes, int n_in,
                              void* d_out, int out_size, void* d_ws, size_t ws_size,
                              hipStream_t stream) {
    const float* x  = (const float*)d_in[0];
    const float* Wa = (const float*)d_in[1];
    const float* ba = (const float*)d_in[2];
    const float* Wp = (const float*)d_in[3];
    const float* bp = (const float*)d_in[4];
    float* out = (float*)d_out;

    // ws (ushort units): xb 4M, Wabt 3M, Wpbt 1M, qkv 12M, yat 4M = 48 MiB
    unsigned short* xb   = (unsigned short*)d_ws;                   // [4096,1024]
    unsigned short* Wabt = xb   + (size_t)T_SEQ * C_DIM;            // [3072,1024] (W^T)
    unsigned short* Wpbt = Wabt + (size_t)C_DIM * QKVW;             // [1024,1024] (W^T)
    unsigned short* qkv  = Wpbt + (size_t)C_DIM * C_DIM;            // [4096,3072]
    unsigned short* yat  = qkv  + (size_t)T_SEQ * QKVW;             // [4096,1024]
    float* part = (float*)d_ws;  // overlays xb (dead after GEMM1); 4.28 MB

    const int n_x = T_SEQ * C_DIM;
    cvt_f32_bf16_kernel<<<n_x / 4 / 256, 256, 0, stream>>>(x, xb, n_x / 4);
    cvt_transpose_kernel<<<dim3(QKVW / 32, C_DIM / 32), 256, 0, stream>>>(
        Wa, Wabt, C_DIM, QKVW);
    cvt_transpose_kernel<<<dim3(C_DIM / 32, C_DIM / 32), 256, 0, stream>>>(
        Wp, Wpbt, C_DIM, C_DIM);

    gemm_nt_kernel<1><<<dim3(QKVW / 128, T_SEQ / 128), 256, 0, stream>>>(
        xb, Wabt, ba, qkv, T_SEQ, QKVW, C_DIM);

    const int nA = H_HEADS * (T_SEQ / 64);          // 1024
    const int nB = H_HEADS * 14;                    // 224
    sparse_attn_mfma<<<nA + nB, 256, 0, stream>>>(qkv, yat, part);
    attn_combine<<<H_HEADS * 2, 64, 0, stream>>>(part, yat);

    gemm_nt_kernel<0><<<dim3(C_DIM / 128, T_SEQ / 128), 256, 0, stream>>>(
        yat, Wpbt, bp, out, T_SEQ, C_DIM, C_DIM);
}